// Round 13
// baseline (1056.364 us; speedup 1.0000x reference)
//
#include <hip/hip_runtime.h>

#define KDIM 512
#define TDIM 64
#define NWAVE 16
#define BLOCK 1024
#define LOG2E 1.4426950408889634f

typedef float v2f __attribute__((ext_vector_type(2)));

// d_ws layout (float offsets) — R8/R11/R12 proven:
#define WS_B2     0
#define WS_XCHG   (KDIM * KDIM)
#define WS_FLAGS  (WS_XCHG + 128 * 2 * 2 * 1024)
#define WS_TOT    (WS_FLAGS + 256)
#define WS_FLOATS (WS_TOT + 256 * 16)

__device__ __forceinline__ float fast_exp2(float v) { return __builtin_amdgcn_exp2f(v); }
__device__ __forceinline__ float fast_rcp(float v)  { return __builtin_amdgcn_rcpf(v); }

// v_add_f32_dpp row_ror:N — full-rate VALU rotation within 16-lane rows.
template <int CTRL>
__device__ __forceinline__ float dpp_add(float v) {
    const int p = __builtin_amdgcn_update_dpp(
        0, __builtin_bit_cast(int, v), CTRL, 0xF, 0xF, true);
    return v + __builtin_bit_cast(float, p);
}

// 64-lane sum: 4 DPP hops (VALU) + 2 DS hops (xor16, xor32).
__device__ __forceinline__ float row_sum64(float v) {
    v = dpp_add<0x121>(v);
    v = dpp_add<0x122>(v);
    v = dpp_add<0x124>(v);
    v = dpp_add<0x128>(v);
    v += __shfl_xor(v, 16, 64);
    v += __shfl_xor(v, 32, 64);
    return v;
}

// 4 independent chains interleaved (latency hiding).
__device__ __forceinline__ void row_sum64_x4(float* s) {
    #pragma unroll
    for (int q = 0; q < 4; ++q) s[q] = dpp_add<0x121>(s[q]);
    #pragma unroll
    for (int q = 0; q < 4; ++q) s[q] = dpp_add<0x122>(s[q]);
    #pragma unroll
    for (int q = 0; q < 4; ++q) s[q] = dpp_add<0x124>(s[q]);
    #pragma unroll
    for (int q = 0; q < 4; ++q) s[q] = dpp_add<0x128>(s[q]);
    float t0 = __shfl_xor(s[0], 16, 64), t1 = __shfl_xor(s[1], 16, 64);
    float t2 = __shfl_xor(s[2], 16, 64), t3 = __shfl_xor(s[3], 16, 64);
    s[0] += t0; s[1] += t1; s[2] += t2; s[3] += t3;
    t0 = __shfl_xor(s[0], 32, 64); t1 = __shfl_xor(s[1], 32, 64);
    t2 = __shfl_xor(s[2], 32, 64); t3 = __shfl_xor(s[3], 32, 64);
    s[0] += t0; s[1] += t1; s[2] += t2; s[3] += t3;
}

__global__ __launch_bounds__(256) void prefold_kernel(
    const float* __restrict__ bias, float* __restrict__ b2)
{
    const int i = blockIdx.x * 256 + threadIdx.x;
    const float4 b = ((const float4*)bias)[i];
    ((float4*)b2)[i] = make_float4(b.x * LOG2E, b.y * LOG2E, b.z * LOG2E, b.w * LOG2E);
}

// R13 = R12 with ONE change: #pragma unroll 2 on the j-loop, exposing two
// iterations' loads (16 float4) to the scheduler so L2-hit latency (~200cyc,
// synchronized across waves by the step barrier) overlaps with the previous
// iteration's exp/fma work. Live set ~120 VGPR < the waves_per_eu(4,4)
// 128-reg budget. Spill tripwire: WRITE_SIZE >> 66.5 MB.
__global__ __launch_bounds__(BLOCK)
__attribute__((amdgpu_waves_per_eu(4, 4)))
void hmm_pair_kernel(
    const float* __restrict__ x,           // [B, T]
    const float* __restrict__ prior_w,     // [K]
    const float* __restrict__ emission_w,  // [K, 2]
    const float* __restrict__ coeff,       // [K, K] raw
    float* __restrict__ ws,                // b2 + exchange + flags + tot
    float* __restrict__ out)               // [B, K]
{
    __shared__ float post[2][KDIM];
    __shared__ float em0s[KDIM];
    __shared__ float emds[KDIM];
    __shared__ float part[NWAVE][2][KDIM];   // 64 KB
    __shared__ float rtmp[NWAVE];
    __shared__ float rn2[2];
    __shared__ float xs[2][TDIM];

    const int gid  = blockIdx.x;
    const int pair = gid & 127;
    const int h    = gid >> 7;             // row half
    const int b0   = 2 * pair;
    const int tid  = threadIdx.x;
    const int lane = tid & 63;
    const int wv   = tid >> 6;
    const int k0   = 4 * lane;
    const int u    = tid >> 9;             // epilogue batch index
    const int k    = tid & 511;            // epilogue k index

    const float* bb = ws + WS_B2;
    int* flags   = (int*)(ws + WS_FLAGS);
    int* my_flag = flags + (pair * 2 + h);
    int* pr_flag = flags + (pair * 2 + (1 - h));
    float* my_slot = ws + WS_XCHG + (size_t)(pair * 2 + h) * 2048;
    float* pr_slot = ws + WS_XCHG + (size_t)(pair * 2 + (1 - h)) * 2048;
    float* my_tot  = ws + WS_TOT + (size_t)(pair * 2 + h) * 16;
    float* pr_tot  = ws + WS_TOT + (size_t)(pair * 2 + (1 - h)) * 16;

    if (tid < 2 * TDIM) xs[tid >> 6][tid & 63] = x[(b0 + (tid >> 6)) * TDIM + (tid & 63)];
    if (tid < KDIM) {
        const float w0 = emission_w[2 * tid + 0];
        const float w1 = emission_w[2 * tid + 1];
        const float e0 = 1.0f / (1.0f + fast_exp2((w1 - w0) * LOG2E));
        em0s[tid] = e0;
        emds[tid] = 1.0f - 2.0f * e0;
    }
    __syncthreads();

    // ---- t = 0: both batches, full K, locally ----
    {
        const float x0 = xs[u][0];
        float v = fast_exp2(prior_w[k] * LOG2E) * fmaf(x0, emds[k], em0s[k]);
        const float s = row_sum64(v);       // waves 0-7: batch0, 8-15: batch1
        if (lane == 0) rtmp[wv] = s;
        __syncthreads();
        const float* rb = &rtmp[u * 8];
        const float tot = ((rb[0] + rb[1]) + (rb[2] + rb[3]))
                        + ((rb[4] + rb[5]) + (rb[6] + rb[7]));
        post[u][k] = v * fast_rcp(tot);
        __syncthreads();
    }

    // ---- steps t = 1 .. T-1 ----
    for (int t = 1; t < TDIM; ++t) {
        v2f acc[2][4];
        #pragma unroll
        for (int uu = 0; uu < 2; ++uu)
            #pragma unroll
            for (int q = 0; q < 4; ++q) acc[uu][q] = (v2f){0.0f, 0.0f};

        // wave wv: row pairs (jA = h*256 + wv + 32*i, jB = jA + 16), i<8
        const float* pc = coeff + (size_t)(h * 256 + wv) * KDIM + k0;
        const float* pb = bb    + (size_t)(h * 256 + wv) * KDIM + k0;

        #pragma unroll 2
        for (int i = 0; i < 8; ++i) {
            const int jA = h * 256 + wv + 32 * i;
            const float4 cA0 = *(const float4*)pc;
            const float4 cA1 = *(const float4*)(pc + 256);
            const float4 cB0 = *(const float4*)(pc + 16 * KDIM);
            const float4 cB1 = *(const float4*)(pc + 16 * KDIM + 256);
            const float4 bA0 = *(const float4*)pb;
            const float4 bA1 = *(const float4*)(pb + 256);
            const float4 bB0 = *(const float4*)(pb + 16 * KDIM);
            const float4 bB1 = *(const float4*)(pb + 16 * KDIM + 256);
            pc += 32 * KDIM; pb += 32 * KDIM;

            const v2f cav[4] = {{cA0.x, cA0.y}, {cA0.z, cA0.w}, {cA1.x, cA1.y}, {cA1.z, cA1.w}};
            const v2f cbv[4] = {{cB0.x, cB0.y}, {cB0.z, cB0.w}, {cB1.x, cB1.y}, {cB1.z, cB1.w}};
            const v2f bav[4] = {{bA0.x, bA0.y}, {bA0.z, bA0.w}, {bA1.x, bA1.y}, {bA1.z, bA1.w}};
            const v2f bbv[4] = {{bB0.x, bB0.y}, {bB0.z, bB0.w}, {bB1.x, bB1.y}, {bB1.z, bB1.w}};

            float p[2][2];
            p[0][0] = post[0][jA]; p[0][1] = post[0][jA + 16];
            p[1][0] = post[1][jA]; p[1][1] = post[1][jA + 16];

            v2f ev[2][2][4];   // [uu][rowAB][q]
            float s[4];
            #pragma unroll
            for (int uu = 0; uu < 2; ++uu) {
                const float pAL = p[uu][0] * LOG2E;
                const float pBL = p[uu][1] * LOG2E;
                const v2f pAv = {pAL, pAL};
                const v2f pBv = {pBL, pBL};
                #pragma unroll
                for (int q = 0; q < 4; ++q) {
                    const v2f aA = __builtin_elementwise_fma(pAv, cav[q], bav[q]);
                    const v2f aB = __builtin_elementwise_fma(pBv, cbv[q], bbv[q]);
                    v2f eA, eB;
                    eA.x = fast_exp2(aA.x); eA.y = fast_exp2(aA.y);
                    eB.x = fast_exp2(aB.x); eB.y = fast_exp2(aB.y);
                    ev[uu][0][q] = eA;
                    ev[uu][1][q] = eB;
                }
                const v2f tA = (ev[uu][0][0] + ev[uu][0][1]) + (ev[uu][0][2] + ev[uu][0][3]);
                const v2f tB = (ev[uu][1][0] + ev[uu][1][1]) + (ev[uu][1][2] + ev[uu][1][3]);
                s[uu * 2 + 0] = tA.x + tA.y;
                s[uu * 2 + 1] = tB.x + tB.y;
            }
            row_sum64_x4(s);

            #pragma unroll
            for (int uu = 0; uu < 2; ++uu) {
                const float scA = p[uu][0] * fast_rcp(s[uu * 2 + 0]);
                const float scB = p[uu][1] * fast_rcp(s[uu * 2 + 1]);
                const v2f scAv = {scA, scA};
                const v2f scBv = {scB, scB};
                #pragma unroll
                for (int q = 0; q < 4; ++q) {
                    acc[uu][q] = __builtin_elementwise_fma(scAv, ev[uu][0][q], acc[uu][q]);
                    acc[uu][q] = __builtin_elementwise_fma(scBv, ev[uu][1][q], acc[uu][q]);
                }
            }
        }

        *(float4*)(&part[wv][0][k0])       = make_float4(acc[0][0].x, acc[0][0].y, acc[0][1].x, acc[0][1].y);
        *(float4*)(&part[wv][0][256 + k0]) = make_float4(acc[0][2].x, acc[0][2].y, acc[0][3].x, acc[0][3].y);
        *(float4*)(&part[wv][1][k0])       = make_float4(acc[1][0].x, acc[1][0].y, acc[1][1].x, acc[1][1].y);
        *(float4*)(&part[wv][1][256 + k0]) = make_float4(acc[1][2].x, acc[1][2].y, acc[1][3].x, acc[1][3].y);
        __syncthreads();                   // barrier A: part visible

        // half-pbe for (u, k) + emission factor + local dot contribution
        float pbe = 0.0f;
        #pragma unroll
        for (int w2 = 0; w2 < NWAVE; ++w2) pbe += part[w2][u][k];
        const float ek = fmaf(xs[u][t], emds[k], em0s[k]);

        // local dot: Σ_k pbe_k·e_k per batch, reduced pre-exchange
        const float wsum = row_sum64(pbe * ek);
        if (lane == 0) rtmp[wv] = wsum;

        // ship pbe to partner
        float* slot = my_slot + (t & 1) * 1024;
        __hip_atomic_store(&slot[tid], pbe, __ATOMIC_RELAXED, __HIP_MEMORY_SCOPE_AGENT);
        __syncthreads();   // drain: LDS rtmp visible + all agent stores complete
        if (tid == 0) {
            const float totl0 = ((rtmp[0] + rtmp[1]) + (rtmp[2] + rtmp[3]))
                              + ((rtmp[4] + rtmp[5]) + (rtmp[6] + rtmp[7]));
            const float totl1 = ((rtmp[8] + rtmp[9]) + (rtmp[10] + rtmp[11]))
                              + ((rtmp[12] + rtmp[13]) + (rtmp[14] + rtmp[15]));
            float* mt = my_tot + (t & 1) * 2;
            __hip_atomic_store(&mt[0], totl0, __ATOMIC_RELAXED, __HIP_MEMORY_SCOPE_AGENT);
            __hip_atomic_store(&mt[1], totl1, __ATOMIC_RELAXED, __HIP_MEMORY_SCOPE_AGENT);
            __hip_atomic_store(my_flag, t, __ATOMIC_RELEASE, __HIP_MEMORY_SCOPE_AGENT);
            int f = __hip_atomic_load(pr_flag, __ATOMIC_ACQUIRE, __HIP_MEMORY_SCOPE_AGENT);
            while (f < t) {
                __builtin_amdgcn_s_sleep(1);
                f = __hip_atomic_load(pr_flag, __ATOMIC_ACQUIRE, __HIP_MEMORY_SCOPE_AGENT);
            }
            const float* pt = pr_tot + (t & 1) * 2;
            const float o0 = __hip_atomic_load(&pt[0], __ATOMIC_RELAXED, __HIP_MEMORY_SCOPE_AGENT);
            const float o1 = __hip_atomic_load(&pt[1], __ATOMIC_RELAXED, __HIP_MEMORY_SCOPE_AGENT);
            rn2[0] = fast_rcp(totl0 + o0);
            rn2[1] = fast_rcp(totl1 + o1);
        }
        __syncthreads();                   // poll-exit: partner data + rn2 ready
        const float* pslot = pr_slot + (t & 1) * 1024;
        const float other = __hip_atomic_load(&pslot[tid], __ATOMIC_RELAXED, __HIP_MEMORY_SCOPE_AGENT);

        post[u][k] = (pbe + other) * ek * rn2[u];
        __syncthreads();                   // barrier C: post visible
    }

    if (tid < KDIM) out[(size_t)(b0 + h) * KDIM + tid] = post[h][tid];
}

// ---------- fallback: single-batch kernel (no workspace needed) ----------
__global__ __launch_bounds__(1024)
__attribute__((amdgpu_waves_per_eu(4, 4)))
void hmm_forward_kernel(
    const float* __restrict__ x, const float* __restrict__ prior_w,
    const float* __restrict__ emission_w, const float* __restrict__ coeff,
    const float* __restrict__ bias, float* __restrict__ out)
{
    __shared__ float post[KDIM];
    __shared__ float em0s[KDIM];
    __shared__ float emds[KDIM];
    __shared__ float part[16][KDIM];
    __shared__ float rtmp[16];
    __shared__ float xs[TDIM];

    const int b = blockIdx.x, tid = threadIdx.x, lane = tid & 63, wv = tid >> 6;
    const int k0 = 4 * lane;

    if (tid < TDIM) xs[tid] = x[b * TDIM + tid];
    if (tid < KDIM) {
        const float w0 = emission_w[2 * tid + 0];
        const float w1 = emission_w[2 * tid + 1];
        const float e0 = 1.0f / (1.0f + fast_exp2((w1 - w0) * LOG2E));
        em0s[tid] = e0;
        emds[tid] = 1.0f - 2.0f * e0;
    }
    __syncthreads();
    {
        const float x0 = xs[0];
        float v = 0.0f;
        if (tid < KDIM)
            v = fast_exp2(prior_w[tid] * LOG2E) * fmaf(x0, emds[tid], em0s[tid]);
        float s = row_sum64(v);
        if (lane == 0) rtmp[wv] = s;
        __syncthreads();
        float tot = 0.0f;
        #pragma unroll
        for (int w2 = 0; w2 < 16; ++w2) tot += rtmp[w2];
        if (tid < KDIM) post[tid] = v * fast_rcp(tot);
        __syncthreads();
    }
    for (int t = 1; t < TDIM; ++t) {
        float acc[8];
        #pragma unroll
        for (int i = 0; i < 8; ++i) acc[i] = 0.0f;
        const float* cA = coeff + (size_t)wv * KDIM + k0;
        const float* bA = bias  + (size_t)wv * KDIM + k0;
        #pragma unroll 1
        for (int i = 0; i < 16; ++i) {
            const float4 cA0 = *(const float4*)cA;
            const float4 cA1 = *(const float4*)(cA + 256);
            const float4 cB0 = *(const float4*)(cA + 16 * KDIM);
            const float4 cB1 = *(const float4*)(cA + 16 * KDIM + 256);
            const float4 bA0 = *(const float4*)bA;
            const float4 bA1 = *(const float4*)(bA + 256);
            const float4 bB0 = *(const float4*)(bA + 16 * KDIM);
            const float4 bB1 = *(const float4*)(bA + 16 * KDIM + 256);
            cA += 32 * KDIM; bA += 32 * KDIM;
            const float pA = post[wv + 32 * i];
            const float pB = post[wv + 16 + 32 * i];
            float s4[4];
            const float eA0 = fast_exp2(fmaf(pA, cA0.x, bA0.x) * LOG2E);
            const float eA1 = fast_exp2(fmaf(pA, cA0.y, bA0.y) * LOG2E);
            const float eA2 = fast_exp2(fmaf(pA, cA0.z, bA0.z) * LOG2E);
            const float eA3 = fast_exp2(fmaf(pA, cA0.w, bA0.w) * LOG2E);
            const float eA4 = fast_exp2(fmaf(pA, cA1.x, bA1.x) * LOG2E);
            const float eA5 = fast_exp2(fmaf(pA, cA1.y, bA1.y) * LOG2E);
            const float eA6 = fast_exp2(fmaf(pA, cA1.z, bA1.z) * LOG2E);
            const float eA7 = fast_exp2(fmaf(pA, cA1.w, bA1.w) * LOG2E);
            const float eB0 = fast_exp2(fmaf(pB, cB0.x, bB0.x) * LOG2E);
            const float eB1 = fast_exp2(fmaf(pB, cB0.y, bB0.y) * LOG2E);
            const float eB2 = fast_exp2(fmaf(pB, cB0.z, bB0.z) * LOG2E);
            const float eB3 = fast_exp2(fmaf(pB, cB0.w, bB0.w) * LOG2E);
            const float eB4 = fast_exp2(fmaf(pB, cB1.x, bB1.x) * LOG2E);
            const float eB5 = fast_exp2(fmaf(pB, cB1.y, bB1.y) * LOG2E);
            const float eB6 = fast_exp2(fmaf(pB, cB1.z, bB1.z) * LOG2E);
            const float eB7 = fast_exp2(fmaf(pB, cB1.w, bB1.w) * LOG2E);
            s4[0] = ((eA0 + eA1) + (eA2 + eA3)) + ((eA4 + eA5) + (eA6 + eA7));
            s4[1] = ((eB0 + eB1) + (eB2 + eB3)) + ((eB4 + eB5) + (eB6 + eB7));
            s4[2] = 0.0f; s4[3] = 0.0f;
            row_sum64_x4(s4);
            const float scA = pA * fast_rcp(s4[0]);
            const float scB = pB * fast_rcp(s4[1]);
            acc[0] = fmaf(scA, eA0, acc[0]); acc[0] = fmaf(scB, eB0, acc[0]);
            acc[1] = fmaf(scA, eA1, acc[1]); acc[1] = fmaf(scB, eB1, acc[1]);
            acc[2] = fmaf(scA, eA2, acc[2]); acc[2] = fmaf(scB, eB2, acc[2]);
            acc[3] = fmaf(scA, eA3, acc[3]); acc[3] = fmaf(scB, eB3, acc[3]);
            acc[4] = fmaf(scA, eA4, acc[4]); acc[4] = fmaf(scB, eB4, acc[4]);
            acc[5] = fmaf(scA, eA5, acc[5]); acc[5] = fmaf(scB, eB5, acc[5]);
            acc[6] = fmaf(scA, eA6, acc[6]); acc[6] = fmaf(scB, eB6, acc[6]);
            acc[7] = fmaf(scA, eA7, acc[7]); acc[7] = fmaf(scB, eB7, acc[7]);
        }
        *(float4*)(&part[wv][k0])       = make_float4(acc[0], acc[1], acc[2], acc[3]);
        *(float4*)(&part[wv][256 + k0]) = make_float4(acc[4], acc[5], acc[6], acc[7]);
        __syncthreads();
        float v = 0.0f;
        if (tid < KDIM) {
            float pbe = 0.0f;
            #pragma unroll
            for (int w2 = 0; w2 < 16; ++w2) pbe += part[w2][tid];
            v = pbe * fmaf(xs[t], emds[tid], em0s[tid]);
        }
        float s = row_sum64(v);
        if (lane == 0) rtmp[wv] = s;
        __syncthreads();
        float tot = 0.0f;
        #pragma unroll
        for (int w2 = 0; w2 < 16; ++w2) tot += rtmp[w2];
        if (tid < KDIM) post[tid] = v * fast_rcp(tot);
        __syncthreads();
    }
    if (tid < KDIM) out[b * KDIM + tid] = post[tid];
}

extern "C" void kernel_launch(void* const* d_in, const int* in_sizes, int n_in,
                              void* d_out, int out_size, void* d_ws, size_t ws_size,
                              hipStream_t stream) {
    const float* x          = (const float*)d_in[0];
    const float* prior_w    = (const float*)d_in[1];
    const float* emission_w = (const float*)d_in[2];
    const float* coeff      = (const float*)d_in[3];
    const float* bias       = (const float*)d_in[4];
    float* out              = (float*)d_out;

    if (ws_size >= (size_t)WS_FLOATS * sizeof(float)) {
        float* ws = (float*)d_ws;
        hipLaunchKernelGGL(prefold_kernel, dim3(KDIM * KDIM / 4 / 256), dim3(256),
                           0, stream, bias, ws + WS_B2);
        hipLaunchKernelGGL(hmm_pair_kernel, dim3(256), dim3(BLOCK), 0, stream,
                           x, prior_w, emission_w, coeff, ws, out);
    } else {
        hipLaunchKernelGGL(hmm_forward_kernel, dim3(256), dim3(1024), 0, stream,
                           x, prior_w, emission_w, coeff, bias, out);
    }
}

// Round 14
// 1009.750 us; speedup vs baseline: 1.0462x; 1.0462x over previous
//
#include <hip/hip_runtime.h>

#define KDIM 512
#define TDIM 64
#define NWAVE 16
#define BLOCK 1024
#define LOG2E 1.4426950408889634f

typedef float v2f __attribute__((ext_vector_type(2)));

// d_ws layout (float offsets) — R8/R11/R12 proven:
#define WS_B2     0
#define WS_XCHG   (KDIM * KDIM)
#define WS_FLAGS  (WS_XCHG + 128 * 2 * 2 * 1024)
#define WS_TOT    (WS_FLAGS + 256)
#define WS_FLOATS (WS_TOT + 256 * 16)

__device__ __forceinline__ float fast_exp2(float v) { return __builtin_amdgcn_exp2f(v); }
__device__ __forceinline__ float fast_rcp(float v)  { return __builtin_amdgcn_rcpf(v); }

// v_add_f32_dpp — full-rate VALU cross-lane adds.
// 0x121/2/4/8 = row_ror:1/2/4/8 (within 16-lane rows)
// 0x142 = row_bcast15 (lane15->lanes16-31, lane47->lanes48-63)
// 0x143 = row_bcast31 (lane31->lanes32-63)
template <int CTRL>
__device__ __forceinline__ float dpp_add(float v) {
    const int p = __builtin_amdgcn_update_dpp(
        0, __builtin_bit_cast(int, v), CTRL, 0xF, 0xF, true);
    return v + __builtin_bit_cast(float, p);
}

// Full 64-lane sum with ZERO DS ops: 6 DPP adds put the total in lane 63,
// readlane broadcasts it as a wave-uniform scalar (SGPR).
__device__ __forceinline__ float wave_total(float v) {
    v = dpp_add<0x121>(v);
    v = dpp_add<0x122>(v);
    v = dpp_add<0x124>(v);
    v = dpp_add<0x128>(v);   // every lane: its 16-lane row sum
    v = dpp_add<0x142>(v);   // rows 1,3 accumulate rows 0,2
    v = dpp_add<0x143>(v);   // lanes 32-63 accumulate lanes 0-31 -> lane 63 = total
    return __builtin_bit_cast(float,
        __builtin_amdgcn_readlane(__builtin_bit_cast(int, v), 63));
}

// 4 independent chains interleaved (latency hiding), all-DPP.
__device__ __forceinline__ void wave_total_x4(float* s) {
    #pragma unroll
    for (int q = 0; q < 4; ++q) s[q] = dpp_add<0x121>(s[q]);
    #pragma unroll
    for (int q = 0; q < 4; ++q) s[q] = dpp_add<0x122>(s[q]);
    #pragma unroll
    for (int q = 0; q < 4; ++q) s[q] = dpp_add<0x124>(s[q]);
    #pragma unroll
    for (int q = 0; q < 4; ++q) s[q] = dpp_add<0x128>(s[q]);
    #pragma unroll
    for (int q = 0; q < 4; ++q) s[q] = dpp_add<0x142>(s[q]);
    #pragma unroll
    for (int q = 0; q < 4; ++q) s[q] = dpp_add<0x143>(s[q]);
    #pragma unroll
    for (int q = 0; q < 4; ++q)
        s[q] = __builtin_bit_cast(float,
            __builtin_amdgcn_readlane(__builtin_bit_cast(int, s[q]), 63));
}

__global__ __launch_bounds__(256) void prefold_kernel(
    const float* __restrict__ bias, float* __restrict__ b2)
{
    const int i = blockIdx.x * 256 + threadIdx.x;
    const float4 b = ((const float4*)bias)[i];
    ((float4*)b2)[i] = make_float4(b.x * LOG2E, b.y * LOG2E, b.z * LOG2E, b.w * LOG2E);
}

// R14 = R12 (unroll 1 restored; R13's unroll-2 was neutral->reverted) with
// the row reductions converted to all-DPP wave_total (no ds_bpermute hops
// anywhere in the hot loop). Exchange protocol untouched (R9/R10 lessons:
// ONE poller per block, one flag, proven flag lines, parity double-buffer).
__global__ __launch_bounds__(BLOCK)
__attribute__((amdgpu_waves_per_eu(4, 4)))
void hmm_pair_kernel(
    const float* __restrict__ x,           // [B, T]
    const float* __restrict__ prior_w,     // [K]
    const float* __restrict__ emission_w,  // [K, 2]
    const float* __restrict__ coeff,       // [K, K] raw
    float* __restrict__ ws,                // b2 + exchange + flags + tot
    float* __restrict__ out)               // [B, K]
{
    __shared__ float post[2][KDIM];
    __shared__ float em0s[KDIM];
    __shared__ float emds[KDIM];
    __shared__ float part[NWAVE][2][KDIM];   // 64 KB
    __shared__ float rtmp[NWAVE];
    __shared__ float rn2[2];
    __shared__ float xs[2][TDIM];

    const int gid  = blockIdx.x;
    const int pair = gid & 127;
    const int h    = gid >> 7;             // row half
    const int b0   = 2 * pair;
    const int tid  = threadIdx.x;
    const int lane = tid & 63;
    const int wv   = tid >> 6;
    const int k0   = 4 * lane;
    const int u    = tid >> 9;             // epilogue batch index
    const int k    = tid & 511;            // epilogue k index

    const float* bb = ws + WS_B2;
    int* flags   = (int*)(ws + WS_FLAGS);
    int* my_flag = flags + (pair * 2 + h);
    int* pr_flag = flags + (pair * 2 + (1 - h));
    float* my_slot = ws + WS_XCHG + (size_t)(pair * 2 + h) * 2048;
    float* pr_slot = ws + WS_XCHG + (size_t)(pair * 2 + (1 - h)) * 2048;
    float* my_tot  = ws + WS_TOT + (size_t)(pair * 2 + h) * 16;
    float* pr_tot  = ws + WS_TOT + (size_t)(pair * 2 + (1 - h)) * 16;

    if (tid < 2 * TDIM) xs[tid >> 6][tid & 63] = x[(b0 + (tid >> 6)) * TDIM + (tid & 63)];
    if (tid < KDIM) {
        const float w0 = emission_w[2 * tid + 0];
        const float w1 = emission_w[2 * tid + 1];
        const float e0 = 1.0f / (1.0f + fast_exp2((w1 - w0) * LOG2E));
        em0s[tid] = e0;
        emds[tid] = 1.0f - 2.0f * e0;
    }
    __syncthreads();

    // ---- t = 0: both batches, full K, locally ----
    {
        const float x0 = xs[u][0];
        float v = fast_exp2(prior_w[k] * LOG2E) * fmaf(x0, emds[k], em0s[k]);
        const float s = wave_total(v);      // waves 0-7: batch0, 8-15: batch1
        if (lane == 0) rtmp[wv] = s;
        __syncthreads();
        const float* rb = &rtmp[u * 8];
        const float tot = ((rb[0] + rb[1]) + (rb[2] + rb[3]))
                        + ((rb[4] + rb[5]) + (rb[6] + rb[7]));
        post[u][k] = v * fast_rcp(tot);
        __syncthreads();
    }

    // ---- steps t = 1 .. T-1 ----
    for (int t = 1; t < TDIM; ++t) {
        v2f acc[2][4];
        #pragma unroll
        for (int uu = 0; uu < 2; ++uu)
            #pragma unroll
            for (int q = 0; q < 4; ++q) acc[uu][q] = (v2f){0.0f, 0.0f};

        // wave wv: row pairs (jA = h*256 + wv + 32*i, jB = jA + 16), i<8
        const float* pc = coeff + (size_t)(h * 256 + wv) * KDIM + k0;
        const float* pb = bb    + (size_t)(h * 256 + wv) * KDIM + k0;

        #pragma unroll 1
        for (int i = 0; i < 8; ++i) {
            const int jA = h * 256 + wv + 32 * i;
            const float4 cA0 = *(const float4*)pc;
            const float4 cA1 = *(const float4*)(pc + 256);
            const float4 cB0 = *(const float4*)(pc + 16 * KDIM);
            const float4 cB1 = *(const float4*)(pc + 16 * KDIM + 256);
            const float4 bA0 = *(const float4*)pb;
            const float4 bA1 = *(const float4*)(pb + 256);
            const float4 bB0 = *(const float4*)(pb + 16 * KDIM);
            const float4 bB1 = *(const float4*)(pb + 16 * KDIM + 256);
            pc += 32 * KDIM; pb += 32 * KDIM;

            const v2f cav[4] = {{cA0.x, cA0.y}, {cA0.z, cA0.w}, {cA1.x, cA1.y}, {cA1.z, cA1.w}};
            const v2f cbv[4] = {{cB0.x, cB0.y}, {cB0.z, cB0.w}, {cB1.x, cB1.y}, {cB1.z, cB1.w}};
            const v2f bav[4] = {{bA0.x, bA0.y}, {bA0.z, bA0.w}, {bA1.x, bA1.y}, {bA1.z, bA1.w}};
            const v2f bbv[4] = {{bB0.x, bB0.y}, {bB0.z, bB0.w}, {bB1.x, bB1.y}, {bB1.z, bB1.w}};

            float p[2][2];
            p[0][0] = post[0][jA]; p[0][1] = post[0][jA + 16];
            p[1][0] = post[1][jA]; p[1][1] = post[1][jA + 16];

            v2f ev[2][2][4];   // [uu][rowAB][q]
            float s[4];
            #pragma unroll
            for (int uu = 0; uu < 2; ++uu) {
                const float pAL = p[uu][0] * LOG2E;
                const float pBL = p[uu][1] * LOG2E;
                const v2f pAv = {pAL, pAL};
                const v2f pBv = {pBL, pBL};
                #pragma unroll
                for (int q = 0; q < 4; ++q) {
                    const v2f aA = __builtin_elementwise_fma(pAv, cav[q], bav[q]);
                    const v2f aB = __builtin_elementwise_fma(pBv, cbv[q], bbv[q]);
                    v2f eA, eB;
                    eA.x = fast_exp2(aA.x); eA.y = fast_exp2(aA.y);
                    eB.x = fast_exp2(aB.x); eB.y = fast_exp2(aB.y);
                    ev[uu][0][q] = eA;
                    ev[uu][1][q] = eB;
                }
                const v2f tA = (ev[uu][0][0] + ev[uu][0][1]) + (ev[uu][0][2] + ev[uu][0][3]);
                const v2f tB = (ev[uu][1][0] + ev[uu][1][1]) + (ev[uu][1][2] + ev[uu][1][3]);
                s[uu * 2 + 0] = tA.x + tA.y;
                s[uu * 2 + 1] = tB.x + tB.y;
            }
            wave_total_x4(s);   // all-DPP: zero DS ops in the row reduction

            #pragma unroll
            for (int uu = 0; uu < 2; ++uu) {
                const float scA = p[uu][0] * fast_rcp(s[uu * 2 + 0]);
                const float scB = p[uu][1] * fast_rcp(s[uu * 2 + 1]);
                const v2f scAv = {scA, scA};
                const v2f scBv = {scB, scB};
                #pragma unroll
                for (int q = 0; q < 4; ++q) {
                    acc[uu][q] = __builtin_elementwise_fma(scAv, ev[uu][0][q], acc[uu][q]);
                    acc[uu][q] = __builtin_elementwise_fma(scBv, ev[uu][1][q], acc[uu][q]);
                }
            }
        }

        *(float4*)(&part[wv][0][k0])       = make_float4(acc[0][0].x, acc[0][0].y, acc[0][1].x, acc[0][1].y);
        *(float4*)(&part[wv][0][256 + k0]) = make_float4(acc[0][2].x, acc[0][2].y, acc[0][3].x, acc[0][3].y);
        *(float4*)(&part[wv][1][k0])       = make_float4(acc[1][0].x, acc[1][0].y, acc[1][1].x, acc[1][1].y);
        *(float4*)(&part[wv][1][256 + k0]) = make_float4(acc[1][2].x, acc[1][2].y, acc[1][3].x, acc[1][3].y);
        __syncthreads();                   // barrier A: part visible

        // half-pbe for (u, k) + emission factor + local dot contribution
        float pbe = 0.0f;
        #pragma unroll
        for (int w2 = 0; w2 < NWAVE; ++w2) pbe += part[w2][u][k];
        const float ek = fmaf(xs[u][t], emds[k], em0s[k]);

        // local dot: Σ_k pbe_k·e_k per batch, reduced pre-exchange
        const float wsum = wave_total(pbe * ek);
        if (lane == 0) rtmp[wv] = wsum;

        // ship pbe to partner
        float* slot = my_slot + (t & 1) * 1024;
        __hip_atomic_store(&slot[tid], pbe, __ATOMIC_RELAXED, __HIP_MEMORY_SCOPE_AGENT);
        __syncthreads();   // drain: LDS rtmp visible + all agent stores complete
        if (tid == 0) {
            const float totl0 = ((rtmp[0] + rtmp[1]) + (rtmp[2] + rtmp[3]))
                              + ((rtmp[4] + rtmp[5]) + (rtmp[6] + rtmp[7]));
            const float totl1 = ((rtmp[8] + rtmp[9]) + (rtmp[10] + rtmp[11]))
                              + ((rtmp[12] + rtmp[13]) + (rtmp[14] + rtmp[15]));
            float* mt = my_tot + (t & 1) * 2;
            __hip_atomic_store(&mt[0], totl0, __ATOMIC_RELAXED, __HIP_MEMORY_SCOPE_AGENT);
            __hip_atomic_store(&mt[1], totl1, __ATOMIC_RELAXED, __HIP_MEMORY_SCOPE_AGENT);
            __hip_atomic_store(my_flag, t, __ATOMIC_RELEASE, __HIP_MEMORY_SCOPE_AGENT);
            int f = __hip_atomic_load(pr_flag, __ATOMIC_ACQUIRE, __HIP_MEMORY_SCOPE_AGENT);
            while (f < t) {
                __builtin_amdgcn_s_sleep(1);
                f = __hip_atomic_load(pr_flag, __ATOMIC_ACQUIRE, __HIP_MEMORY_SCOPE_AGENT);
            }
            const float* pt = pr_tot + (t & 1) * 2;
            const float o0 = __hip_atomic_load(&pt[0], __ATOMIC_RELAXED, __HIP_MEMORY_SCOPE_AGENT);
            const float o1 = __hip_atomic_load(&pt[1], __ATOMIC_RELAXED, __HIP_MEMORY_SCOPE_AGENT);
            rn2[0] = fast_rcp(totl0 + o0);
            rn2[1] = fast_rcp(totl1 + o1);
        }
        __syncthreads();                   // poll-exit: partner data + rn2 ready
        const float* pslot = pr_slot + (t & 1) * 1024;
        const float other = __hip_atomic_load(&pslot[tid], __ATOMIC_RELAXED, __HIP_MEMORY_SCOPE_AGENT);

        post[u][k] = (pbe + other) * ek * rn2[u];
        __syncthreads();                   // barrier C: post visible
    }

    if (tid < KDIM) out[(size_t)(b0 + h) * KDIM + tid] = post[h][tid];
}

// ---------- fallback: single-batch kernel (no workspace needed) ----------
__global__ __launch_bounds__(1024)
__attribute__((amdgpu_waves_per_eu(4, 4)))
void hmm_forward_kernel(
    const float* __restrict__ x, const float* __restrict__ prior_w,
    const float* __restrict__ emission_w, const float* __restrict__ coeff,
    const float* __restrict__ bias, float* __restrict__ out)
{
    __shared__ float post[KDIM];
    __shared__ float em0s[KDIM];
    __shared__ float emds[KDIM];
    __shared__ float part[16][KDIM];
    __shared__ float rtmp[16];
    __shared__ float xs[TDIM];

    const int b = blockIdx.x, tid = threadIdx.x, lane = tid & 63, wv = tid >> 6;
    const int k0 = 4 * lane;

    if (tid < TDIM) xs[tid] = x[b * TDIM + tid];
    if (tid < KDIM) {
        const float w0 = emission_w[2 * tid + 0];
        const float w1 = emission_w[2 * tid + 1];
        const float e0 = 1.0f / (1.0f + fast_exp2((w1 - w0) * LOG2E));
        em0s[tid] = e0;
        emds[tid] = 1.0f - 2.0f * e0;
    }
    __syncthreads();
    {
        const float x0 = xs[0];
        float v = 0.0f;
        if (tid < KDIM)
            v = fast_exp2(prior_w[tid] * LOG2E) * fmaf(x0, emds[tid], em0s[tid]);
        float s = wave_total(v);
        if (lane == 0) rtmp[wv] = s;
        __syncthreads();
        float tot = 0.0f;
        #pragma unroll
        for (int w2 = 0; w2 < 16; ++w2) tot += rtmp[w2];
        if (tid < KDIM) post[tid] = v * fast_rcp(tot);
        __syncthreads();
    }
    for (int t = 1; t < TDIM; ++t) {
        float acc[8];
        #pragma unroll
        for (int i = 0; i < 8; ++i) acc[i] = 0.0f;
        const float* cA = coeff + (size_t)wv * KDIM + k0;
        const float* bA = bias  + (size_t)wv * KDIM + k0;
        #pragma unroll 1
        for (int i = 0; i < 16; ++i) {
            const float4 cA0 = *(const float4*)cA;
            const float4 cA1 = *(const float4*)(cA + 256);
            const float4 cB0 = *(const float4*)(cA + 16 * KDIM);
            const float4 cB1 = *(const float4*)(cA + 16 * KDIM + 256);
            const float4 bA0 = *(const float4*)bA;
            const float4 bA1 = *(const float4*)(bA + 256);
            const float4 bB0 = *(const float4*)(bA + 16 * KDIM);
            const float4 bB1 = *(const float4*)(bA + 16 * KDIM + 256);
            cA += 32 * KDIM; bA += 32 * KDIM;
            const float pA = post[wv + 32 * i];
            const float pB = post[wv + 16 + 32 * i];
            float s4[4];
            const float eA0 = fast_exp2(fmaf(pA, cA0.x, bA0.x) * LOG2E);
            const float eA1 = fast_exp2(fmaf(pA, cA0.y, bA0.y) * LOG2E);
            const float eA2 = fast_exp2(fmaf(pA, cA0.z, bA0.z) * LOG2E);
            const float eA3 = fast_exp2(fmaf(pA, cA0.w, bA0.w) * LOG2E);
            const float eA4 = fast_exp2(fmaf(pA, cA1.x, bA1.x) * LOG2E);
            const float eA5 = fast_exp2(fmaf(pA, cA1.y, bA1.y) * LOG2E);
            const float eA6 = fast_exp2(fmaf(pA, cA1.z, bA1.z) * LOG2E);
            const float eA7 = fast_exp2(fmaf(pA, cA1.w, bA1.w) * LOG2E);
            const float eB0 = fast_exp2(fmaf(pB, cB0.x, bB0.x) * LOG2E);
            const float eB1 = fast_exp2(fmaf(pB, cB0.y, bB0.y) * LOG2E);
            const float eB2 = fast_exp2(fmaf(pB, cB0.z, bB0.z) * LOG2E);
            const float eB3 = fast_exp2(fmaf(pB, cB0.w, bB0.w) * LOG2E);
            const float eB4 = fast_exp2(fmaf(pB, cB1.x, bB1.x) * LOG2E);
            const float eB5 = fast_exp2(fmaf(pB, cB1.y, bB1.y) * LOG2E);
            const float eB6 = fast_exp2(fmaf(pB, cB1.z, bB1.z) * LOG2E);
            const float eB7 = fast_exp2(fmaf(pB, cB1.w, bB1.w) * LOG2E);
            s4[0] = ((eA0 + eA1) + (eA2 + eA3)) + ((eA4 + eA5) + (eA6 + eA7));
            s4[1] = ((eB0 + eB1) + (eB2 + eB3)) + ((eB4 + eB5) + (eB6 + eB7));
            s4[2] = 0.0f; s4[3] = 0.0f;
            wave_total_x4(s4);
            const float scA = pA * fast_rcp(s4[0]);
            const float scB = pB * fast_rcp(s4[1]);
            acc[0] = fmaf(scA, eA0, acc[0]); acc[0] = fmaf(scB, eB0, acc[0]);
            acc[1] = fmaf(scA, eA1, acc[1]); acc[1] = fmaf(scB, eB1, acc[1]);
            acc[2] = fmaf(scA, eA2, acc[2]); acc[2] = fmaf(scB, eB2, acc[2]);
            acc[3] = fmaf(scA, eA3, acc[3]); acc[3] = fmaf(scB, eB3, acc[3]);
            acc[4] = fmaf(scA, eA4, acc[4]); acc[4] = fmaf(scB, eB4, acc[4]);
            acc[5] = fmaf(scA, eA5, acc[5]); acc[5] = fmaf(scB, eB5, acc[5]);
            acc[6] = fmaf(scA, eA6, acc[6]); acc[6] = fmaf(scB, eB6, acc[6]);
            acc[7] = fmaf(scA, eA7, acc[7]); acc[7] = fmaf(scB, eB7, acc[7]);
        }
        *(float4*)(&part[wv][k0])       = make_float4(acc[0], acc[1], acc[2], acc[3]);
        *(float4*)(&part[wv][256 + k0]) = make_float4(acc[4], acc[5], acc[6], acc[7]);
        __syncthreads();
        float v = 0.0f;
        if (tid < KDIM) {
            float pbe = 0.0f;
            #pragma unroll
            for (int w2 = 0; w2 < 16; ++w2) pbe += part[w2][tid];
            v = pbe * fmaf(xs[t], emds[tid], em0s[tid]);
        }
        float s = wave_total(v);
        if (lane == 0) rtmp[wv] = s;
        __syncthreads();
        float tot = 0.0f;
        #pragma unroll
        for (int w2 = 0; w2 < 16; ++w2) tot += rtmp[w2];
        if (tid < KDIM) post[tid] = v * fast_rcp(tot);
        __syncthreads();
    }
    if (tid < KDIM) out[b * KDIM + tid] = post[tid];
}

extern "C" void kernel_launch(void* const* d_in, const int* in_sizes, int n_in,
                              void* d_out, int out_size, void* d_ws, size_t ws_size,
                              hipStream_t stream) {
    const float* x          = (const float*)d_in[0];
    const float* prior_w    = (const float*)d_in[1];
    const float* emission_w = (const float*)d_in[2];
    const float* coeff      = (const float*)d_in[3];
    const float* bias       = (const float*)d_in[4];
    float* out              = (float*)d_out;

    if (ws_size >= (size_t)WS_FLOATS * sizeof(float)) {
        float* ws = (float*)d_ws;
        hipLaunchKernelGGL(prefold_kernel, dim3(KDIM * KDIM / 4 / 256), dim3(256),
                           0, stream, bias, ws + WS_B2);
        hipLaunchKernelGGL(hmm_pair_kernel, dim3(256), dim3(BLOCK), 0, stream,
                           x, prior_w, emission_w, coeff, ws, out);
    } else {
        hipLaunchKernelGGL(hmm_forward_kernel, dim3(256), dim3(1024), 0, stream,
                           x, prior_w, emission_w, coeff, bias, out);
    }
}